// Round 1
// baseline (251.524 us; speedup 1.0000x reference)
//
#include <hip/hip_runtime.h>
#include <stdint.h>

typedef __bf16 bf16x8 __attribute__((ext_vector_type(8)));
typedef __bf16 bf16x4v __attribute__((ext_vector_type(4)));
typedef float  f32x16 __attribute__((ext_vector_type(16)));
typedef float  f32x4t __attribute__((ext_vector_type(4)));
typedef unsigned int u32x2 __attribute__((ext_vector_type(2)));

// ---- ws layout (bytes) ----
#define WS_W1S 0            // 32 chunks  * 1 KB = 32 KB   W1e fragment-swizzled
#define WS_W2S 32768        // 128 chunks * 1 KB = 128 KB  W2 fragment-swizzled
#define WS_R   163840       // 4*256*256 f32 = 1 MiB   Rt[b][n][o] (incl. b1)
#define WS_CT  1212416      // 4*256*256 bf16 = 512 KB Ct[b][m][o]

// ---------------- merged pre-kernel: weights + rank-1 terms ----------------
// blocks 0..39: weights -> bf16, MFMA-fragment-swizzled (same mapping as before:
// o = wid*64 + mb*32 + (lane&31), k = ks*16 + (lane>>5)*8 + j).
// blocks 40..295: R/C rank-1 terms, 4 j per thread (was 16) -> 4x more blocks,
// covers all 256 CUs instead of 64 (prep_rc was ~1 wave/SIMD on 1/4 of chip).
__global__ __launch_bounds__(256) void prep_all(
    const float* __restrict__ W1, const float* __restrict__ b1,
    const float* __restrict__ W2, const float* __restrict__ node,
    __bf16* __restrict__ w1s, __bf16* __restrict__ w2s,
    float* __restrict__ Rt, __bf16* __restrict__ Ctb) {
    __shared__ float nds[128 * 4];
    const int blk = blockIdx.x;
    if (blk < 40) {                           // ---- weight swizzle part ----
        int t = blk * 256 + threadIdx.x;      // 40*256 = 160 chunks * 64 lanes
        int chunk = t >> 6, lane = t & 63;
        if (chunk < 128) {                    // W2: 4 wid x 16 ks x 2 mb
            int wid = chunk >> 5, ks = (chunk >> 1) & 15, mb = chunk & 1;
            int o = wid * 64 + mb * 32 + (lane & 31);
            int k = ks * 16 + (lane >> 5) * 8;
            const float* src = W2 + o * 256 + k;
            __bf16* dst = w2s + chunk * 512 + lane * 8;
#pragma unroll
            for (int j = 0; j < 8; ++j) dst[j] = (__bf16)src[j];
        } else if (chunk < 160) {             // W1e: 4 wid x 4 ks x 2 mb
            int c1 = chunk - 128;
            int wid = c1 >> 3, ks = (c1 >> 1) & 3, mb = c1 & 1;
            int o = wid * 64 + mb * 32 + (lane & 31);
            int k = ks * 16 + (lane >> 5) * 8;
            const float* src = W1 + o * 320 + k;
            __bf16* dst = w1s + c1 * 512 + lane * 8;
#pragma unroll
            for (int j = 0; j < 8; ++j) dst[j] = (__bf16)src[j];
        }
        return;
    }
    // ---- rank-1 part: rcb = b*64 + jg, 4 j per thread, o = tid ----
    const int rcb = blk - 40;
    const int b = rcb >> 6, j0 = (rcb & 63) << 2;
    const int o = threadIdx.x;
    if (o < 128)
        *(float4*)&nds[o * 4] = *(const float4*)(node + b * 32768 + o * 256 + j0);
    __syncthreads();
    float aR[4] = {0.f, 0.f, 0.f, 0.f};
    float aC[4] = {0.f, 0.f, 0.f, 0.f};
    const float* wr = W1 + o * 320 + 64;
    const float* wc = W1 + o * 320 + 192;
    for (int c4 = 0; c4 < 32; ++c4) {
        float4 wrv = *(const float4*)(wr + c4 * 4);
        float4 wcv = *(const float4*)(wc + c4 * 4);
        const float* wrp = (const float*)&wrv;
        const float* wcp = (const float*)&wcv;
#pragma unroll
        for (int r = 0; r < 4; ++r) {
            f32x4t n4 = *(const f32x4t*)&nds[(c4 * 4 + r) * 4];  // wave-uniform broadcast
#pragma unroll
            for (int q = 0; q < 4; ++q) {
                aR[q] = fmaf(wrp[r], n4[q], aR[q]);
                aC[q] = fmaf(wcp[r], n4[q], aC[q]);
            }
        }
    }
    float bb = b1[o];
#pragma unroll
    for (int j = 0; j < 4; ++j) {
        int idx = ((b * 256 + j0 + j) << 8) + o;
        Rt[idx] = aR[j] + bb;
        Ctb[idx] = (__bf16)aC[j];
    }
}

// ---------------- main fused kernel ----------------
// 256 thr (4 waves x 64 och), grid 1024 (was 512): n-groups of 4 -> 3 blocks/CU
// resident (LDS 48.9 KB x3 = 147 KB <= 160 KB), launch_bounds(256,3) caps VGPR
// at 170 so 3 waves/SIMD fit. This is the occupancy lever: counters showed
// MfmaUtil 25 / VALU 22 / HBM 7% / Occ 18.8 -> latency-bound, grid 512 = exactly
// 2 blocks/CU was the cap.
// Weight A-fragments streamed from L2 each tile via SWIZZLED layout ->
// fully coalesced (1 KB contiguous per wave-load). asm barrier per iteration
// is load-bearing: defeats LICM re-hoist into persistent regs -> spill
// (R2/R3 lesson: 75 MB scratch WRITE, MfmaUtil 7.5%).
__device__ inline void zero_acc(f32x16 acc[2][2]) {
#pragma unroll
    for (int i = 0; i < 2; ++i)
#pragma unroll
        for (int j = 0; j < 2; ++j)
#pragma unroll
            for (int k = 0; k < 16; ++k) acc[i][j][k] = 0.f;
}

__global__ __launch_bounds__(256, 3) void fused_main(
    const float* __restrict__ edge, const __bf16* __restrict__ w1s,
    const __bf16* __restrict__ w2s, const float* __restrict__ Rt,
    const __bf16* __restrict__ Ctb, const float* __restrict__ b2,
    const float* __restrict__ W3, const float* __restrict__ b3,
    float* __restrict__ out) {
    __shared__ unsigned int lds_e[64 * 34];   // edge tile [m][e-pair], stride 34 dw (8B-aligned rows -> b64 reads)
    __shared__ unsigned int lds_h1[64 * 140]; // h1 tile [pix][ch/2], stride 140 dw
    __shared__ float lds_p[64 * 9];
    __shared__ float lds_c[512];              // [0..255]=b2, [256..511]=W3

    const int tid = threadIdx.x;
    const int wid = tid >> 6;
    const int lane = tid & 63;
    const int p31 = lane & 31;
    const int hi = lane >> 5;
    const int obase = wid * 64;

    const int blk = blockIdx.x;
    const int b   = blk >> 8;
    const int m0  = ((blk >> 6) & 3) << 6;
    const int n0  = (blk & 63) << 2;

    lds_c[tid] = b2[tid];
    lds_c[256 + tid] = W3[tid];

    const float4* eg = (const float4*)edge;
    const int a_ = tid & 15;
    const int epb = tid >> 4;
    float4 pf[4];

#define PREFETCH(nn)                                                        \
    {                                                                       \
        _Pragma("unroll")                                                   \
        for (int r = 0; r < 2; ++r) {                                       \
            int ep = r * 16 + epb;                                          \
            int f4 = (b * 64 + ep * 2) * 16384 + (nn) * 64 + (m0 >> 2) + a_;\
            pf[r * 2]     = eg[f4];                                         \
            pf[r * 2 + 1] = eg[f4 + 16384];                                 \
        }                                                                   \
    }

    // coalesced: chunk = (wid*16 + ksg)*2 + mb, lane-consecutive 16 B
#define LOAD_Q(bf, q)                                                       \
    {                                                                       \
        _Pragma("unroll")                                                   \
        for (int ksl = 0; ksl < 4; ++ksl)                                   \
            _Pragma("unroll")                                               \
            for (int mb = 0; mb < 2; ++mb)                                  \
                A2q[bf][ksl][mb] = *(const bf16x8*)(w2_s +                  \
                    ((((wid << 4) + (q) * 4 + ksl) << 1) + mb) * 512 + (lane << 3)); \
    }

    PREFETCH(n0);

    // ---- hoisted it-invariant Ct fragments (32 regs, gather once/block) ----
    bf16x4v CvR[8][2];
#pragma unroll
    for (int mb = 0; mb < 2; ++mb)
#pragma unroll
        for (int rg = 0; rg < 4; ++rg)
#pragma unroll
            for (int nb = 0; nb < 2; ++nb)
                CvR[mb * 4 + rg][nb] = *(const bf16x4v*)(Ctb +
                    ((b * 256 + m0 + nb * 32 + p31) << 8) + obase + mb * 32 + 8 * rg + 4 * hi);

    f32x16 acc[2][2];
    bf16x8 A2q[2][4][2];
#pragma unroll 1
    for (int it = 0; it < 4; ++it) {
        const int n = n0 + it;

        // opaque per-iteration address barriers: defeat LICM/CSE of weight loads
        uint64_t w1a = (uint64_t)w1s;
        asm volatile("" : "+s"(w1a));
        const __bf16* w1_s = (const __bf16*)w1a;
        uint64_t w2a = (uint64_t)w2s;
        asm volatile("" : "+s"(w2a));
        const __bf16* w2_s = (const __bf16*)w2a;

        // ---- stage pf -> lds_e (transpose to [m][e], bf16) ----
#pragma unroll
        for (int r = 0; r < 2; ++r) {
            int ep = r * 16 + epb;
            const float* p0 = (const float*)&pf[r * 2];
            const float* p1 = (const float*)&pf[r * 2 + 1];
#pragma unroll
            for (int i = 0; i < 4; ++i) {
                union { __bf16 h[2]; unsigned int u; } t;
                t.h[0] = (__bf16)p0[i];
                t.h[1] = (__bf16)p1[i];
                lds_e[(a_ * 4 + i) * 34 + ep] = t.u;
            }
        }
        // ---- A1 (W1e) fragments: coalesced stream from L2 ----
        bf16x8 A1[2][4];
#pragma unroll
        for (int mb = 0; mb < 2; ++mb)
#pragma unroll
            for (int ks = 0; ks < 4; ++ks)
                A1[mb][ks] = *(const bf16x8*)(w1_s +
                    ((((wid << 2) + ks) << 1) + mb) * 512 + (lane << 3));
        // ---- Rt row prefetch (L2 broadcast) issued pre-barrier: latency hides
        //      under layer-1 MFMAs instead of stalling epilogue 1 ----
        const int nRow = (b * 256 + n) << 8;
        f32x4t Rv[2][4];
#pragma unroll
        for (int mb = 0; mb < 2; ++mb)
#pragma unroll
            for (int rg = 0; rg < 4; ++rg)
                Rv[mb][rg] = *(const f32x4t*)(Rt + nRow + obase + mb * 32 + 8 * rg + 4 * hi);
        __syncthreads();

        // ---- layer 1: W1e(64K) @ edge ----
        zero_acc(acc);
#pragma unroll
        for (int ks = 0; ks < 4; ++ks) {
            bf16x8 B1[2];
#pragma unroll
            for (int nb = 0; nb < 2; ++nb) {
                union { u32x2 d[2]; bf16x8 v; } bb;
                const unsigned int* base = &lds_e[(nb * 32 + p31) * 34 + ks * 8 + hi * 4];
                bb.d[0] = *(const u32x2*)base;         // merged ds_read2_b64 /
                bb.d[1] = *(const u32x2*)(base + 2);   // 2x ds_read_b64 (was 4x b32)
                B1[nb] = bb.v;
            }
#pragma unroll
            for (int mb = 0; mb < 2; ++mb) {
                acc[mb][0] = __builtin_amdgcn_mfma_f32_32x32x16_bf16(A1[mb][ks], B1[0], acc[mb][0], 0, 0, 0);
                acc[mb][1] = __builtin_amdgcn_mfma_f32_32x32x16_bf16(A1[mb][ks], B1[1], acc[mb][1], 0, 0, 0);
            }
        }

        // ---- epilogue 1: + Rt[n] (prefetched) + Ct (regs), relu -> lds_h1 ----
#pragma unroll
        for (int mb = 0; mb < 2; ++mb) {
#pragma unroll
            for (int rg = 0; rg < 4; ++rg) {
                int och = obase + mb * 32 + 8 * rg + 4 * hi;
                f32x4t Rvv = Rv[mb][rg];
#pragma unroll
                for (int nb = 0; nb < 2; ++nb) {
                    int pix = nb * 32 + p31;
                    bf16x4v Cv = CvR[mb * 4 + rg][nb];
                    union { __bf16 h[4]; u32x2 u; } t;
#pragma unroll
                    for (int rr = 0; rr < 4; ++rr) {
                        float v = acc[mb][nb][rg * 4 + rr] + Rvv[rr] + (float)Cv[rr];
                        t.h[rr] = (__bf16)fmaxf(v, 0.f);
                    }
                    *(u32x2*)&lds_h1[pix * 140 + (och >> 1)] = t.u;
                }
            }
        }
        // ---- prefetches overlapping the barrier + layer-2 start ----
        LOAD_Q(0, 0);
        if (it < 3) PREFETCH(n + 1);
        __syncthreads();

        // ---- layer 2: W2(256K) @ h1, rolling streamed quarter window ----
        zero_acc(acc);
#pragma unroll
        for (int q = 0; q < 4; ++q) {
            if (q < 3) LOAD_Q((q + 1) & 1, q + 1);
#pragma unroll
            for (int ksl = 0; ksl < 4; ++ksl) {
                const int ksg = q * 4 + ksl;
                bf16x8 B2[2];
#pragma unroll
                for (int nb = 0; nb < 2; ++nb)
                    B2[nb] = *(const bf16x8*)&lds_h1[(nb * 32 + p31) * 140 + ksg * 8 + hi * 4];
#pragma unroll
                for (int mb = 0; mb < 2; ++mb) {
                    acc[mb][0] = __builtin_amdgcn_mfma_f32_32x32x16_bf16(A2q[q & 1][ksl][mb], B2[0], acc[mb][0], 0, 0, 0);
                    acc[mb][1] = __builtin_amdgcn_mfma_f32_32x32x16_bf16(A2q[q & 1][ksl][mb], B2[1], acc[mb][1], 0, 0, 0);
                }
            }
        }

        // ---- epilogue 2: +b2, relu, dot W3 (fp32, from LDS) ----
        float part0 = 0.f, part1 = 0.f;
#pragma unroll
        for (int mb = 0; mb < 2; ++mb) {
#pragma unroll
            for (int rg = 0; rg < 4; ++rg) {
                int och = obase + mb * 32 + 8 * rg + 4 * hi;
                f32x4t b2v = *(const f32x4t*)&lds_c[och];
                f32x4t w3v = *(const f32x4t*)&lds_c[256 + och];
#pragma unroll
                for (int rr = 0; rr < 4; ++rr) {
                    float h0 = fmaxf(acc[mb][0][rg * 4 + rr] + b2v[rr], 0.f);
                    float h1v = fmaxf(acc[mb][1][rg * 4 + rr] + b2v[rr], 0.f);
                    part0 = fmaf(w3v[rr], h0, part0);
                    part1 = fmaf(w3v[rr], h1v, part1);
                }
            }
        }
        lds_p[(0 * 32 + p31) * 9 + wid * 2 + hi] = part0;
        lds_p[(1 * 32 + p31) * 9 + wid * 2 + hi] = part1;
        __syncthreads();

        if (tid < 64) {
            float s = b3[0];
#pragma unroll
            for (int k = 0; k < 8; ++k) s += lds_p[tid * 9 + k];
            out[((b * 256 + n) << 8) + m0 + tid] = s;
        }
    }
#undef PREFETCH
#undef LOAD_Q
}

extern "C" void kernel_launch(void* const* d_in, const int* in_sizes, int n_in,
                              void* d_out, int out_size, void* d_ws, size_t ws_size,
                              hipStream_t stream) {
    const float* edge = (const float*)d_in[0];
    const float* node = (const float*)d_in[1];
    const float* W1   = (const float*)d_in[2];
    const float* b1   = (const float*)d_in[3];
    const float* W2   = (const float*)d_in[4];
    const float* b2   = (const float*)d_in[5];
    const float* W3   = (const float*)d_in[6];
    const float* b3   = (const float*)d_in[7];
    char* ws = (char*)d_ws;
    __bf16* w1s = (__bf16*)(ws + WS_W1S);
    __bf16* w2s = (__bf16*)(ws + WS_W2S);
    float*  Rt  = (float*)(ws + WS_R);
    __bf16* Ctb = (__bf16*)(ws + WS_CT);

    prep_all<<<296, 256, 0, stream>>>(W1, b1, W2, node, w1s, w2s, Rt, Ctb);
    fused_main<<<1024, 256, 0, stream>>>(edge, w1s, w2s, Rt, Ctb, b2, W3, b3, (float*)d_out);
}

// Round 2
// 156.361 us; speedup vs baseline: 1.6086x; 1.6086x over previous
//
#include <hip/hip_runtime.h>
#include <stdint.h>

typedef __bf16 bf16x8 __attribute__((ext_vector_type(8)));
typedef __bf16 bf16x4v __attribute__((ext_vector_type(4)));
typedef float  f32x16 __attribute__((ext_vector_type(16)));
typedef float  f32x4t __attribute__((ext_vector_type(4)));
typedef unsigned int u32x2 __attribute__((ext_vector_type(2)));

// ---- ws layout (bytes) ----
#define WS_W1S 0            // 32 chunks  * 1 KB = 32 KB   W1e fragment-swizzled
#define WS_W2S 32768        // 128 chunks * 1 KB = 128 KB  W2 fragment-swizzled
#define WS_R   163840       // 4*256*256 f32 = 1 MiB   Rt[b][n][o] (incl. b1)
#define WS_CT  1212416      // 4*256*256 bf16 = 512 KB Ct[b][m][o]

// ---------------- merged pre-kernel: weights + rank-1 terms ----------------
// blocks 0..39: weights -> bf16, MFMA-fragment-swizzled (mapping must match
// fused_main: o = wid*64 + mb*32 + (lane&31), k = ks*16 + (lane>>5)*8 + j).
// blocks 40..295: R/C rank-1 terms, 4 j per thread -> covers all 256 CUs.
__global__ __launch_bounds__(256) void prep_all(
    const float* __restrict__ W1, const float* __restrict__ b1,
    const float* __restrict__ W2, const float* __restrict__ node,
    __bf16* __restrict__ w1s, __bf16* __restrict__ w2s,
    float* __restrict__ Rt, __bf16* __restrict__ Ctb) {
    __shared__ float nds[128 * 4];
    const int blk = blockIdx.x;
    if (blk < 40) {                           // ---- weight swizzle part ----
        int t = blk * 256 + threadIdx.x;      // 40*256 = 160 chunks * 64 lanes
        int chunk = t >> 6, lane = t & 63;
        if (chunk < 128) {                    // W2: 4 wid x 16 ks x 2 mb
            int wid = chunk >> 5, ks = (chunk >> 1) & 15, mb = chunk & 1;
            int o = wid * 64 + mb * 32 + (lane & 31);
            int k = ks * 16 + (lane >> 5) * 8;
            const float* src = W2 + o * 256 + k;
            __bf16* dst = w2s + chunk * 512 + lane * 8;
#pragma unroll
            for (int j = 0; j < 8; ++j) dst[j] = (__bf16)src[j];
        } else if (chunk < 160) {             // W1e: 4 wid x 4 ks x 2 mb
            int c1 = chunk - 128;
            int wid = c1 >> 3, ks = (c1 >> 1) & 3, mb = c1 & 1;
            int o = wid * 64 + mb * 32 + (lane & 31);
            int k = ks * 16 + (lane >> 5) * 8;
            const float* src = W1 + o * 320 + k;
            __bf16* dst = w1s + c1 * 512 + lane * 8;
#pragma unroll
            for (int j = 0; j < 8; ++j) dst[j] = (__bf16)src[j];
        }
        return;
    }
    // ---- rank-1 part: rcb = b*64 + jg, 4 j per thread, o = tid ----
    const int rcb = blk - 40;
    const int b = rcb >> 6, j0 = (rcb & 63) << 2;
    const int o = threadIdx.x;
    if (o < 128)
        *(float4*)&nds[o * 4] = *(const float4*)(node + b * 32768 + o * 256 + j0);
    __syncthreads();
    float aR[4] = {0.f, 0.f, 0.f, 0.f};
    float aC[4] = {0.f, 0.f, 0.f, 0.f};
    const float* wr = W1 + o * 320 + 64;
    const float* wc = W1 + o * 320 + 192;
    for (int c4 = 0; c4 < 32; ++c4) {
        float4 wrv = *(const float4*)(wr + c4 * 4);
        float4 wcv = *(const float4*)(wc + c4 * 4);
        const float* wrp = (const float*)&wrv;
        const float* wcp = (const float*)&wcv;
#pragma unroll
        for (int r = 0; r < 4; ++r) {
            f32x4t n4 = *(const f32x4t*)&nds[(c4 * 4 + r) * 4];  // wave-uniform broadcast
#pragma unroll
            for (int q = 0; q < 4; ++q) {
                aR[q] = fmaf(wrp[r], n4[q], aR[q]);
                aC[q] = fmaf(wcp[r], n4[q], aC[q]);
            }
        }
    }
    float bb = b1[o];
#pragma unroll
    for (int j = 0; j < 4; ++j) {
        int idx = ((b * 256 + j0 + j) << 8) + o;
        Rt[idx] = aR[j] + bb;
        Ctb[idx] = (__bf16)aC[j];
    }
}

// ---------------- main fused kernel ----------------
// 256 thr (4 waves x 64 och), grid 512, 8 n-rows per block.
// __launch_bounds__(256,2): the per-wave UNIFIED reg budget is 256 (VGPR+AGPR
// share one file on gfx950). True demand ~190 (64 AGPR acc + ~128 VGPR).
// R1 post-mortem: (256,3) caps the budget at 170 -> 104 MB scratch WRITE,
// MfmaUtil 10.8%, VGPR_Count 84. 3 waves/SIMD is unreachable at this state
// size; do NOT raise the bound without first removing >24 regs of live state.
// Weight A-fragments streamed from L2 each tile via SWIZZLED layout ->
// fully coalesced (1 KB contiguous per wave-load). asm barrier per iteration
// is load-bearing: defeats LICM re-hoist into persistent regs -> spill
// (R2/R3 lesson: 75 MB scratch WRITE, MfmaUtil 7.5%).
// Two barriers per iteration; per-iteration partials land in a per-it lds_p
// slice, single reduction barrier after the loop (was 3 barriers + serialized
// tid<64 tail per iteration).
__device__ inline void zero_acc(f32x16 acc[2][2]) {
#pragma unroll
    for (int i = 0; i < 2; ++i)
#pragma unroll
        for (int j = 0; j < 2; ++j)
#pragma unroll
            for (int k = 0; k < 16; ++k) acc[i][j][k] = 0.f;
}

__global__ __launch_bounds__(256, 2) void fused_main(
    const float* __restrict__ edge, const __bf16* __restrict__ w1s,
    const __bf16* __restrict__ w2s, const float* __restrict__ Rt,
    const __bf16* __restrict__ Ctb, const float* __restrict__ b2,
    const float* __restrict__ W3, const float* __restrict__ b3,
    float* __restrict__ out) {
    __shared__ unsigned int lds_e[64 * 34];   // edge tile [m][e-pair], stride 34 dw (8B rows -> b64 reads)
    __shared__ unsigned int lds_h1[64 * 140]; // h1 tile [pix][ch/2], stride 140 dw
    __shared__ float lds_p[8 * 64 * 9];       // per-iteration partials [it][pix][slot]
    __shared__ float lds_c[512];              // [0..255]=b2, [256..511]=W3

    const int tid = threadIdx.x;
    const int wid = tid >> 6;
    const int lane = tid & 63;
    const int p31 = lane & 31;
    const int hi = lane >> 5;
    const int obase = wid * 64;

    const int blk = blockIdx.x;
    const int b   = blk >> 7;
    const int m0  = ((blk >> 5) & 3) << 6;
    const int n0  = (blk & 31) << 3;

    lds_c[tid] = b2[tid];
    lds_c[256 + tid] = W3[tid];

    const float4* eg = (const float4*)edge;
    const int a_ = tid & 15;
    const int epb = tid >> 4;
    float4 pf[4];

#define PREFETCH(nn)                                                        \
    {                                                                       \
        _Pragma("unroll")                                                   \
        for (int r = 0; r < 2; ++r) {                                       \
            int ep = r * 16 + epb;                                          \
            int f4 = (b * 64 + ep * 2) * 16384 + (nn) * 64 + (m0 >> 2) + a_;\
            pf[r * 2]     = eg[f4];                                         \
            pf[r * 2 + 1] = eg[f4 + 16384];                                 \
        }                                                                   \
    }

    // coalesced: chunk = (wid*16 + ksg)*2 + mb, lane-consecutive 16 B
#define LOAD_Q(bf, q)                                                       \
    {                                                                       \
        _Pragma("unroll")                                                   \
        for (int ksl = 0; ksl < 4; ++ksl)                                   \
            _Pragma("unroll")                                               \
            for (int mb = 0; mb < 2; ++mb)                                  \
                A2q[bf][ksl][mb] = *(const bf16x8*)(w2_s +                  \
                    ((((wid << 4) + (q) * 4 + ksl) << 1) + mb) * 512 + (lane << 3)); \
    }

    PREFETCH(n0);

    // ---- hoisted it-invariant Ct fragments (32 regs, gather once/block) ----
    bf16x4v CvR[8][2];
#pragma unroll
    for (int mb = 0; mb < 2; ++mb)
#pragma unroll
        for (int rg = 0; rg < 4; ++rg)
#pragma unroll
            for (int nb = 0; nb < 2; ++nb)
                CvR[mb * 4 + rg][nb] = *(const bf16x4v*)(Ctb +
                    ((b * 256 + m0 + nb * 32 + p31) << 8) + obase + mb * 32 + 8 * rg + 4 * hi);

    f32x16 acc[2][2];
    bf16x8 A2q[2][4][2];
    for (int it = 0; it < 8; ++it) {
        const int n = n0 + it;

        // opaque per-iteration address barriers: defeat LICM/CSE of weight loads
        uint64_t w1a = (uint64_t)w1s;
        asm volatile("" : "+s"(w1a));
        const __bf16* w1_s = (const __bf16*)w1a;
        uint64_t w2a = (uint64_t)w2s;
        asm volatile("" : "+s"(w2a));
        const __bf16* w2_s = (const __bf16*)w2a;

        // ---- stage pf -> lds_e (transpose to [m][e], bf16) ----
#pragma unroll
        for (int r = 0; r < 2; ++r) {
            int ep = r * 16 + epb;
            const float* p0 = (const float*)&pf[r * 2];
            const float* p1 = (const float*)&pf[r * 2 + 1];
#pragma unroll
            for (int i = 0; i < 4; ++i) {
                union { __bf16 h[2]; unsigned int u; } t;
                t.h[0] = (__bf16)p0[i];
                t.h[1] = (__bf16)p1[i];
                lds_e[(a_ * 4 + i) * 34 + ep] = t.u;
            }
        }
        // ---- A1 (W1e) fragments: coalesced stream from L2 ----
        bf16x8 A1[2][4];
#pragma unroll
        for (int mb = 0; mb < 2; ++mb)
#pragma unroll
            for (int ks = 0; ks < 4; ++ks)
                A1[mb][ks] = *(const bf16x8*)(w1_s +
                    ((((wid << 2) + ks) << 1) + mb) * 512 + (lane << 3));
        // ---- Rt row prefetch (L2 broadcast) issued pre-barrier: its ~300cy
        //      L2 latency hides under barrier1 + layer-1 MFMAs instead of
        //      stalling epilogue 1 (R0 loaded it mid-epilogue) ----
        const int nRow = (b * 256 + n) << 8;
        f32x4t Rv[2][4];
#pragma unroll
        for (int mb = 0; mb < 2; ++mb)
#pragma unroll
            for (int rg = 0; rg < 4; ++rg)
                Rv[mb][rg] = *(const f32x4t*)(Rt + nRow + obase + mb * 32 + 8 * rg + 4 * hi);
        __syncthreads();

        // ---- layer 1: W1e(64K) @ edge ----
        zero_acc(acc);
#pragma unroll
        for (int ks = 0; ks < 4; ++ks) {
            bf16x8 B1[2];
#pragma unroll
            for (int nb = 0; nb < 2; ++nb) {
                union { u32x2 d[2]; bf16x8 v; } bb;
                const unsigned int* base = &lds_e[(nb * 32 + p31) * 34 + ks * 8 + hi * 4];
                bb.d[0] = *(const u32x2*)base;         // 2x ds_read_b64 (was 4x b32)
                bb.d[1] = *(const u32x2*)(base + 2);
                B1[nb] = bb.v;
            }
#pragma unroll
            for (int mb = 0; mb < 2; ++mb) {
                acc[mb][0] = __builtin_amdgcn_mfma_f32_32x32x16_bf16(A1[mb][ks], B1[0], acc[mb][0], 0, 0, 0);
                acc[mb][1] = __builtin_amdgcn_mfma_f32_32x32x16_bf16(A1[mb][ks], B1[1], acc[mb][1], 0, 0, 0);
            }
        }

        // ---- epilogue 1: + Rt[n] (prefetched) + Ct (regs), relu -> lds_h1 ----
#pragma unroll
        for (int mb = 0; mb < 2; ++mb) {
#pragma unroll
            for (int rg = 0; rg < 4; ++rg) {
                int och = obase + mb * 32 + 8 * rg + 4 * hi;
                f32x4t Rvv = Rv[mb][rg];
#pragma unroll
                for (int nb = 0; nb < 2; ++nb) {
                    int pix = nb * 32 + p31;
                    bf16x4v Cv = CvR[mb * 4 + rg][nb];
                    union { __bf16 h[4]; u32x2 u; } t;
#pragma unroll
                    for (int rr = 0; rr < 4; ++rr) {
                        float v = acc[mb][nb][rg * 4 + rr] + Rvv[rr] + (float)Cv[rr];
                        t.h[rr] = (__bf16)fmaxf(v, 0.f);
                    }
                    *(u32x2*)&lds_h1[pix * 140 + (och >> 1)] = t.u;
                }
            }
        }
        // ---- prefetches overlapping the barrier + layer-2 start ----
        LOAD_Q(0, 0);
        if (it < 7) PREFETCH(n + 1);
        __syncthreads();

        // ---- layer 2: W2(256K) @ h1, rolling streamed quarter window ----
        zero_acc(acc);
#pragma unroll
        for (int q = 0; q < 4; ++q) {
            if (q < 3) LOAD_Q((q + 1) & 1, q + 1);
#pragma unroll
            for (int ksl = 0; ksl < 4; ++ksl) {
                const int ksg = q * 4 + ksl;
                bf16x8 B2[2];
#pragma unroll
                for (int nb = 0; nb < 2; ++nb)
                    B2[nb] = *(const bf16x8*)&lds_h1[(nb * 32 + p31) * 140 + ksg * 8 + hi * 4];
#pragma unroll
                for (int mb = 0; mb < 2; ++mb) {
                    acc[mb][0] = __builtin_amdgcn_mfma_f32_32x32x16_bf16(A2q[q & 1][ksl][mb], B2[0], acc[mb][0], 0, 0, 0);
                    acc[mb][1] = __builtin_amdgcn_mfma_f32_32x32x16_bf16(A2q[q & 1][ksl][mb], B2[1], acc[mb][1], 0, 0, 0);
                }
            }
        }

        // ---- epilogue 2: +b2, relu, dot W3 (fp32, from LDS) -> per-it lds_p
        //      slice; NO barrier here (hazards covered by barriers 1/2 of the
        //      next iteration; lds_p slices are disjoint per it) ----
        float part0 = 0.f, part1 = 0.f;
#pragma unroll
        for (int mb = 0; mb < 2; ++mb) {
#pragma unroll
            for (int rg = 0; rg < 4; ++rg) {
                int och = obase + mb * 32 + 8 * rg + 4 * hi;
                f32x4t b2v = *(const f32x4t*)&lds_c[och];
                f32x4t w3v = *(const f32x4t*)&lds_c[256 + och];
#pragma unroll
                for (int rr = 0; rr < 4; ++rr) {
                    float h0 = fmaxf(acc[mb][0][rg * 4 + rr] + b2v[rr], 0.f);
                    float h1v = fmaxf(acc[mb][1][rg * 4 + rr] + b2v[rr], 0.f);
                    part0 = fmaf(w3v[rr], h0, part0);
                    part1 = fmaf(w3v[rr], h1v, part1);
                }
            }
        }
        lds_p[(it * 64 + 0 * 32 + p31) * 9 + wid * 2 + hi] = part0;
        lds_p[(it * 64 + 1 * 32 + p31) * 9 + wid * 2 + hi] = part1;
    }

    // ---- single final reduction: 512 outputs (8 rows x 64 m), 2/thread ----
    __syncthreads();
    {
        float bb3 = b3[0];
#pragma unroll
        for (int r = 0; r < 2; ++r) {
            int idx = r * 256 + tid;      // 0..511
            int row = idx >> 6;           // it 0..7
            int mm  = idx & 63;
            float s = bb3;
#pragma unroll
            for (int k = 0; k < 8; ++k) s += lds_p[(row * 64 + mm) * 9 + k];
            out[((b * 256 + n0 + row) << 8) + m0 + mm] = s;
        }
    }
#undef PREFETCH
#undef LOAD_Q
}

extern "C" void kernel_launch(void* const* d_in, const int* in_sizes, int n_in,
                              void* d_out, int out_size, void* d_ws, size_t ws_size,
                              hipStream_t stream) {
    const float* edge = (const float*)d_in[0];
    const float* node = (const float*)d_in[1];
    const float* W1   = (const float*)d_in[2];
    const float* b1   = (const float*)d_in[3];
    const float* W2   = (const float*)d_in[4];
    const float* b2   = (const float*)d_in[5];
    const float* W3   = (const float*)d_in[6];
    const float* b3   = (const float*)d_in[7];
    char* ws = (char*)d_ws;
    __bf16* w1s = (__bf16*)(ws + WS_W1S);
    __bf16* w2s = (__bf16*)(ws + WS_W2S);
    float*  Rt  = (float*)(ws + WS_R);
    __bf16* Ctb = (__bf16*)(ws + WS_CT);

    prep_all<<<296, 256, 0, stream>>>(W1, b1, W2, node, w1s, w2s, Rt, Ctb);
    fused_main<<<512, 256, 0, stream>>>(edge, w1s, w2s, Rt, Ctb, b2, W3, b3, (float*)d_out);
}

// Round 3
// 153.220 us; speedup vs baseline: 1.6416x; 1.0205x over previous
//
#include <hip/hip_runtime.h>
#include <stdint.h>

typedef __bf16 bf16x8 __attribute__((ext_vector_type(8)));
typedef __bf16 bf16x4v __attribute__((ext_vector_type(4)));
typedef float  f32x16 __attribute__((ext_vector_type(16)));
typedef float  f32x4t __attribute__((ext_vector_type(4)));
typedef unsigned int u32x2 __attribute__((ext_vector_type(2)));

// ---- ws layout (bytes) ----
#define WS_W1S 0            // 32 chunks  * 1 KB = 32 KB   W1e fragment-swizzled
#define WS_W2S 32768        // 128 chunks * 1 KB = 128 KB  W2 fragment-swizzled
#define WS_R   163840       // 4*256*256 f32 = 1 MiB   Rt[b][n][o] (incl. b1)
#define WS_CT  1212416      // 4*256*256 bf16 = 512 KB Ct[b][m][o]

// ---------------- merged pre-kernel: weights + rank-1 terms ----------------
__global__ __launch_bounds__(256) void prep_all(
    const float* __restrict__ W1, const float* __restrict__ b1,
    const float* __restrict__ W2, const float* __restrict__ node,
    __bf16* __restrict__ w1s, __bf16* __restrict__ w2s,
    float* __restrict__ Rt, __bf16* __restrict__ Ctb) {
    __shared__ float nds[128 * 4];
    const int blk = blockIdx.x;
    if (blk < 40) {                           // ---- weight swizzle part ----
        int t = blk * 256 + threadIdx.x;      // 40*256 = 160 chunks * 64 lanes
        int chunk = t >> 6, lane = t & 63;
        if (chunk < 128) {                    // W2: 4 wid x 16 ks x 2 mb
            int wid = chunk >> 5, ks = (chunk >> 1) & 15, mb = chunk & 1;
            int o = wid * 64 + mb * 32 + (lane & 31);
            int k = ks * 16 + (lane >> 5) * 8;
            const float* src = W2 + o * 256 + k;
            __bf16* dst = w2s + chunk * 512 + lane * 8;
#pragma unroll
            for (int j = 0; j < 8; ++j) dst[j] = (__bf16)src[j];
        } else if (chunk < 160) {             // W1e: 4 wid x 4 ks x 2 mb
            int c1 = chunk - 128;
            int wid = c1 >> 3, ks = (c1 >> 1) & 3, mb = c1 & 1;
            int o = wid * 64 + mb * 32 + (lane & 31);
            int k = ks * 16 + (lane >> 5) * 8;
            const float* src = W1 + o * 320 + k;
            __bf16* dst = w1s + c1 * 512 + lane * 8;
#pragma unroll
            for (int j = 0; j < 8; ++j) dst[j] = (__bf16)src[j];
        }
        return;
    }
    // ---- rank-1 part: rcb = b*64 + jg, 4 j per thread, o = tid ----
    const int rcb = blk - 40;
    const int b = rcb >> 6, j0 = (rcb & 63) << 2;
    const int o = threadIdx.x;
    if (o < 128)
        *(float4*)&nds[o * 4] = *(const float4*)(node + b * 32768 + o * 256 + j0);
    __syncthreads();
    float aR[4] = {0.f, 0.f, 0.f, 0.f};
    float aC[4] = {0.f, 0.f, 0.f, 0.f};
    const float* wr = W1 + o * 320 + 64;
    const float* wc = W1 + o * 320 + 192;
    for (int c4 = 0; c4 < 32; ++c4) {
        float4 wrv = *(const float4*)(wr + c4 * 4);
        float4 wcv = *(const float4*)(wc + c4 * 4);
        const float* wrp = (const float*)&wrv;
        const float* wcp = (const float*)&wcv;
#pragma unroll
        for (int r = 0; r < 4; ++r) {
            f32x4t n4 = *(const f32x4t*)&nds[(c4 * 4 + r) * 4];  // wave-uniform broadcast
#pragma unroll
            for (int q = 0; q < 4; ++q) {
                aR[q] = fmaf(wrp[r], n4[q], aR[q]);
                aC[q] = fmaf(wcp[r], n4[q], aC[q]);
            }
        }
    }
    float bb = b1[o];
#pragma unroll
    for (int j = 0; j < 4; ++j) {
        int idx = ((b * 256 + j0 + j) << 8) + o;
        Rt[idx] = aR[j] + bb;
        Ctb[idx] = (__bf16)aC[j];
    }
}

// ---------------- main fused kernel ----------------
// 256 thr (4 waves x 64 och), grid 512, 8 n-rows per block, 2 blocks/CU.
// __launch_bounds__(256,2): per-wave UNIFIED reg budget 256 (VGPR+AGPR share
// one file on gfx950). R1 post-mortem: (256,3)=170 budget -> 104 MB scratch,
// MfmaUtil 10.8. Do NOT raise.
// R3: raw LDS-only barriers. __syncthreads() drains vmcnt(0) (all global
// loads!) at every barrier -> the pre-barrier HBM PREFETCH (~900cy) and L2
// streams stalled the whole block each iteration. This kernel has NO
// cross-wave global hazards (all global loads land in private regs; ws is
// read-only here), so barriers only need lgkmcnt (LDS) ordering. Hazards:
// lds_e writes(it+1) vs reads(it) ordered by barrier2(it); lds_h1 writes(it+1)
// vs reads(it) by barrier1(it+1); every wave drains its own lgkm before
// entering a barrier, so reads complete before any overwriter exits it.
__device__ __forceinline__ void lds_barrier() {
    __builtin_amdgcn_sched_barrier(0);
    asm volatile("s_waitcnt lgkmcnt(0)" ::: "memory");
    __builtin_amdgcn_s_barrier();
    __builtin_amdgcn_sched_barrier(0);
}

__device__ inline void zero_acc(f32x16 acc[2][2]) {
#pragma unroll
    for (int i = 0; i < 2; ++i)
#pragma unroll
        for (int j = 0; j < 2; ++j)
#pragma unroll
            for (int k = 0; k < 16; ++k) acc[i][j][k] = 0.f;
}

__global__ __launch_bounds__(256, 2) void fused_main(
    const float* __restrict__ edge, const __bf16* __restrict__ w1s,
    const __bf16* __restrict__ w2s, const float* __restrict__ Rt,
    const __bf16* __restrict__ Ctb, const float* __restrict__ b2,
    const float* __restrict__ W3, const float* __restrict__ b3,
    float* __restrict__ out) {
    __shared__ unsigned int lds_e[64 * 34];   // edge tile [m][e-pair], stride 34 dw
    __shared__ unsigned int lds_h1[64 * 140]; // h1 tile [pix][ch/2], stride 140 dw
    __shared__ float lds_p[8 * 64 * 9];       // per-iteration partials [it][pix][slot]
    __shared__ float lds_c[512];              // [0..255]=b2, [256..511]=W3

    const int tid = threadIdx.x;
    const int wid = tid >> 6;
    const int lane = tid & 63;
    const int p31 = lane & 31;
    const int hi = lane >> 5;
    const int obase = wid * 64;

    const int blk = blockIdx.x;
    const int b   = blk >> 7;
    const int m0  = ((blk >> 5) & 3) << 6;
    const int n0  = (blk & 31) << 3;

    lds_c[tid] = b2[tid];
    lds_c[256 + tid] = W3[tid];

    const float4* eg = (const float4*)edge;
    const int a_ = tid & 15;
    const int epb = tid >> 4;
    float4 pf[4];

#define PREFETCH(nn)                                                        \
    {                                                                       \
        _Pragma("unroll")                                                   \
        for (int r = 0; r < 2; ++r) {                                       \
            int ep = r * 16 + epb;                                          \
            int f4 = (b * 64 + ep * 2) * 16384 + (nn) * 64 + (m0 >> 2) + a_;\
            pf[r * 2]     = eg[f4];                                         \
            pf[r * 2 + 1] = eg[f4 + 16384];                                 \
        }                                                                   \
    }

    // coalesced: chunk = (wid*16 + ksg)*2 + mb, lane-consecutive 16 B
#define LOAD_Q(bf, q)                                                       \
    {                                                                       \
        _Pragma("unroll")                                                   \
        for (int ksl = 0; ksl < 4; ++ksl)                                   \
            _Pragma("unroll")                                               \
            for (int mb = 0; mb < 2; ++mb)                                  \
                A2q[bf][ksl][mb] = *(const bf16x8*)(w2_s +                  \
                    ((((wid << 4) + (q) * 4 + ksl) << 1) + mb) * 512 + (lane << 3)); \
    }

    PREFETCH(n0);

    // ---- hoisted it-invariant Ct fragments (32 regs, gather once/block) ----
    bf16x4v CvR[8][2];
#pragma unroll
    for (int mb = 0; mb < 2; ++mb)
#pragma unroll
        for (int rg = 0; rg < 4; ++rg)
#pragma unroll
            for (int nb = 0; nb < 2; ++nb)
                CvR[mb * 4 + rg][nb] = *(const bf16x4v*)(Ctb +
                    ((b * 256 + m0 + nb * 32 + p31) << 8) + obase + mb * 32 + 8 * rg + 4 * hi);

    // ---- A1 (W1e) fragments: loop-invariant, persist in regs (32 VGPR) ----
    bf16x8 A1[2][4];
#pragma unroll
    for (int mb = 0; mb < 2; ++mb)
#pragma unroll
        for (int ks = 0; ks < 4; ++ks)
            A1[mb][ks] = *(const bf16x8*)(w1s +
                ((((wid << 2) + ks) << 1) + mb) * 512 + (lane << 3));

    f32x16 acc[2][2];
    bf16x8 A2q[2][4][2];
    for (int it = 0; it < 8; ++it) {
        const int n = n0 + it;

        // opaque per-iteration address barrier: defeat LICM/CSE of W2 loads
        // (full A2q persistence = 128 regs -> spill; A1 is only 32, persisted)
        uint64_t w2a = (uint64_t)w2s;
        asm volatile("" : "+s"(w2a));
        const __bf16* w2_s = (const __bf16*)w2a;

        // ---- stage pf -> lds_e (transpose to [m][e], bf16) ----
#pragma unroll
        for (int r = 0; r < 2; ++r) {
            int ep = r * 16 + epb;
            const float* p0 = (const float*)&pf[r * 2];
            const float* p1 = (const float*)&pf[r * 2 + 1];
#pragma unroll
            for (int i = 0; i < 4; ++i) {
                union { __bf16 h[2]; unsigned int u; } t;
                t.h[0] = (__bf16)p0[i];
                t.h[1] = (__bf16)p1[i];
                lds_e[(a_ * 4 + i) * 34 + ep] = t.u;
            }
        }
        // ---- next-row HBM prefetch issued EARLY (pf regs dead after stage);
        //      ~900cy latency spans barrier1+layer1+epi1+barrier2 (raw
        //      barriers don't drain vmcnt) ----
        if (it < 7) PREFETCH(n + 1);

        // ---- Rt row prefetch (L2 broadcast), consumed in epilogue 1 ----
        const int nRow = (b * 256 + n) << 8;
        f32x4t Rv[2][4];
#pragma unroll
        for (int mb = 0; mb < 2; ++mb)
#pragma unroll
            for (int rg = 0; rg < 4; ++rg)
                Rv[mb][rg] = *(const f32x4t*)(Rt + nRow + obase + mb * 32 + 8 * rg + 4 * hi);

        lds_barrier();

        // ---- layer 1: W1e(64K) @ edge ----
        zero_acc(acc);
#pragma unroll
        for (int ks = 0; ks < 4; ++ks) {
            bf16x8 B1[2];
#pragma unroll
            for (int nb = 0; nb < 2; ++nb) {
                union { u32x2 d[2]; bf16x8 v; } bb;
                const unsigned int* base = &lds_e[(nb * 32 + p31) * 34 + ks * 8 + hi * 4];
                bb.d[0] = *(const u32x2*)base;
                bb.d[1] = *(const u32x2*)(base + 2);
                B1[nb] = bb.v;
            }
#pragma unroll
            for (int mb = 0; mb < 2; ++mb) {
                acc[mb][0] = __builtin_amdgcn_mfma_f32_32x32x16_bf16(A1[mb][ks], B1[0], acc[mb][0], 0, 0, 0);
                acc[mb][1] = __builtin_amdgcn_mfma_f32_32x32x16_bf16(A1[mb][ks], B1[1], acc[mb][1], 0, 0, 0);
            }
        }

        // ---- epilogue 1: + Rt[n] + Ct (regs), relu -> lds_h1 ----
#pragma unroll
        for (int mb = 0; mb < 2; ++mb) {
#pragma unroll
            for (int rg = 0; rg < 4; ++rg) {
                int och = obase + mb * 32 + 8 * rg + 4 * hi;
                f32x4t Rvv = Rv[mb][rg];
#pragma unroll
                for (int nb = 0; nb < 2; ++nb) {
                    int pix = nb * 32 + p31;
                    bf16x4v Cv = CvR[mb * 4 + rg][nb];
                    union { __bf16 h[4]; u32x2 u; } t;
#pragma unroll
                    for (int rr = 0; rr < 4; ++rr) {
                        float v = acc[mb][nb][rg * 4 + rr] + Rvv[rr] + (float)Cv[rr];
                        t.h[rr] = (__bf16)fmaxf(v, 0.f);
                    }
                    *(u32x2*)&lds_h1[pix * 140 + (och >> 1)] = t.u;
                }
            }
        }
        // ---- W2 quarter-0 prefetch overlapping the barrier ----
        LOAD_Q(0, 0);
        lds_barrier();

        // ---- layer 2: W2(256K) @ h1, rolling streamed quarter window ----
        zero_acc(acc);
        __builtin_amdgcn_s_setprio(1);
#pragma unroll
        for (int q = 0; q < 4; ++q) {
            if (q < 3) LOAD_Q((q + 1) & 1, q + 1);
#pragma unroll
            for (int ksl = 0; ksl < 4; ++ksl) {
                const int ksg = q * 4 + ksl;
                bf16x8 B2[2];
#pragma unroll
                for (int nb = 0; nb < 2; ++nb)
                    B2[nb] = *(const bf16x8*)&lds_h1[(nb * 32 + p31) * 140 + ksg * 8 + hi * 4];
#pragma unroll
                for (int mb = 0; mb < 2; ++mb) {
                    acc[mb][0] = __builtin_amdgcn_mfma_f32_32x32x16_bf16(A2q[q & 1][ksl][mb], B2[0], acc[mb][0], 0, 0, 0);
                    acc[mb][1] = __builtin_amdgcn_mfma_f32_32x32x16_bf16(A2q[q & 1][ksl][mb], B2[1], acc[mb][1], 0, 0, 0);
                }
            }
        }
        __builtin_amdgcn_s_setprio(0);

        // ---- epilogue 2: +b2, relu, dot W3 -> per-it lds_p slice ----
        float part0 = 0.f, part1 = 0.f;
#pragma unroll
        for (int mb = 0; mb < 2; ++mb) {
#pragma unroll
            for (int rg = 0; rg < 4; ++rg) {
                int och = obase + mb * 32 + 8 * rg + 4 * hi;
                f32x4t b2v = *(const f32x4t*)&lds_c[och];
                f32x4t w3v = *(const f32x4t*)&lds_c[256 + och];
#pragma unroll
                for (int rr = 0; rr < 4; ++rr) {
                    float h0 = fmaxf(acc[mb][0][rg * 4 + rr] + b2v[rr], 0.f);
                    float h1v = fmaxf(acc[mb][1][rg * 4 + rr] + b2v[rr], 0.f);
                    part0 = fmaf(w3v[rr], h0, part0);
                    part1 = fmaf(w3v[rr], h1v, part1);
                }
            }
        }
        lds_p[(it * 64 + 0 * 32 + p31) * 9 + wid * 2 + hi] = part0;
        lds_p[(it * 64 + 1 * 32 + p31) * 9 + wid * 2 + hi] = part1;
    }

    // ---- single final reduction: 512 outputs (8 rows x 64 m), 2/thread ----
    __syncthreads();
    {
        float bb3 = b3[0];
#pragma unroll
        for (int r = 0; r < 2; ++r) {
            int idx = r * 256 + tid;      // 0..511
            int row = idx >> 6;           // it 0..7
            int mm  = idx & 63;
            float s = bb3;
#pragma unroll
            for (int k = 0; k < 8; ++k) s += lds_p[(row * 64 + mm) * 9 + k];
            out[((b * 256 + n0 + row) << 8) + m0 + mm] = s;
        }
    }
#undef PREFETCH
#undef LOAD_Q
}

extern "C" void kernel_launch(void* const* d_in, const int* in_sizes, int n_in,
                              void* d_out, int out_size, void* d_ws, size_t ws_size,
                              hipStream_t stream) {
    const float* edge = (const float*)d_in[0];
    const float* node = (const float*)d_in[1];
    const float* W1   = (const float*)d_in[2];
    const float* b1   = (const float*)d_in[3];
    const float* W2   = (const float*)d_in[4];
    const float* b2   = (const float*)d_in[5];
    const float* W3   = (const float*)d_in[6];
    const float* b3   = (const float*)d_in[7];
    char* ws = (char*)d_ws;
    __bf16* w1s = (__bf16*)(ws + WS_W1S);
    __bf16* w2s = (__bf16*)(ws + WS_W2S);
    float*  Rt  = (float*)(ws + WS_R);
    __bf16* Ctb = (__bf16*)(ws + WS_CT);

    prep_all<<<296, 256, 0, stream>>>(W1, b1, W2, node, w1s, w2s, Rt, Ctb);
    fused_main<<<512, 256, 0, stream>>>(edge, w1s, w2s, Rt, Ctb, b2, W3, b3, (float*)d_out);
}